// Round 1
// baseline (247.799 us; speedup 1.0000x reference)
//
#include <hip/hip_runtime.h>
#include <stdint.h>

typedef __bf16 bf16;
typedef __bf16 bf16x8 __attribute__((ext_vector_type(8)));
typedef __bf16 bf16x4 __attribute__((ext_vector_type(4)));
typedef float f32x4 __attribute__((ext_vector_type(4)));

constexpr int nB = 2, nS = 2048, nD = 768, nH = 12, nDK = 64;
constexpr int nM = nB * nS;  // 4096
constexpr float LN_EPS = 1e-5f;

static __device__ __forceinline__ f32x4 mfma16(bf16x8 a, bf16x8 b, f32x4 c) {
  return __builtin_amdgcn_mfma_f32_16x16x32_bf16(a, b, c, 0, 0, 0);
}

// ---------------- prep: x -> bf16 ----------------
__global__ __launch_bounds__(256) void k_prep_x(const float* __restrict__ x,
                                                bf16* __restrict__ xb) {
  int i = (blockIdx.x * 256 + threadIdx.x) * 4;
  float4 v = *(const float4*)(x + i);
  bf16x4 o;
  o[0] = (bf16)v.x; o[1] = (bf16)v.y; o[2] = (bf16)v.z; o[3] = (bf16)v.w;
  *(bf16x4*)(xb + i) = o;
}

// ---------------- prep: weights -> bf16, transposed to [n][k] ----------------
__global__ __launch_bounds__(256) void k_prep_w(
    const float* __restrict__ w0, const float* __restrict__ w1,
    const float* __restrict__ w2, const float* __restrict__ w3,
    const float* __restrict__ w4, bf16* __restrict__ wt) {
  __shared__ float tb[64][65];
  int w = blockIdx.z;
  const float* src = (w == 0) ? w0 : (w == 1) ? w1 : (w == 2) ? w2 : (w == 3) ? w3 : w4;
  int k0 = blockIdx.y * 64, n0 = blockIdx.x * 64;
  int tx = threadIdx.x & 63, ty = threadIdx.x >> 6;
#pragma unroll
  for (int it = 0; it < 16; ++it) {
    int r = it * 4 + ty;
    tb[r][tx] = src[(size_t)(k0 + r) * nD + n0 + tx];
  }
  __syncthreads();
  bf16* dst = wt + (size_t)w * nD * nD;
#pragma unroll
  for (int it = 0; it < 16; ++it) {
    int r = it * 4 + ty;
    dst[(size_t)(n0 + r) * nD + k0 + tx] = (bf16)tb[tx][r];
  }
}

// ---------------- QPKV GEMM: C = X @ W (Wt is W^T), 128x128 tile, BK=64 ----------------
// z = 0..3 selects {Wq->qf, Wp->pf, Wk->kf, Wv->vt(transposed layout)}
__global__ __launch_bounds__(256) void k_gemm_qpkv(
    const bf16* __restrict__ xb, const bf16* __restrict__ wt,
    bf16* __restrict__ qf, bf16* __restrict__ pf, bf16* __restrict__ kf_,
    bf16* __restrict__ vt) {
  __shared__ alignas(16) char smem[32768];
  char* As = smem;
  char* Bs = smem + 16384;
  int t = threadIdx.x, lane = t & 63, w = t >> 6;
  int fr = lane & 15, fg = lane >> 4;
  int wm = w >> 1, wn = w & 1;
  int widx = blockIdx.z;
  int m0 = blockIdx.y * 128, n0 = blockIdx.x * 128;
  const bf16* wbase = wt + (size_t)widx * nD * nD;
  int srow = t >> 3;       // 0..31 (row within 32-row staging slab)
  int scol = (t & 7) * 8;  // element col 0..56

  f32x4 acc[4][4];
#pragma unroll
  for (int i = 0; i < 4; ++i)
#pragma unroll
    for (int j = 0; j < 4; ++j) acc[i][j] = (f32x4){0.f, 0.f, 0.f, 0.f};

  for (int kt = 0; kt < nD / 64; ++kt) {
    int k0 = kt * 64;
#pragma unroll
    for (int inst = 0; inst < 4; ++inst) {
      int row = inst * 32 + srow;
      int phys = row * 128 + (((t & 7) * 16) ^ ((row & 7) << 4));
      *(bf16x8*)(As + phys) = *(const bf16x8*)(xb + (size_t)(m0 + row) * nD + k0 + scol);
      *(bf16x8*)(Bs + phys) = *(const bf16x8*)(wbase + (size_t)(n0 + row) * nD + k0 + scol);
    }
    __syncthreads();
#pragma unroll
    for (int ks = 0; ks < 2; ++ks) {
      bf16x8 af[4], bfr[4];
#pragma unroll
      for (int i = 0; i < 4; ++i) {
        int row = wm * 64 + i * 16 + fr;
        af[i] = *(const bf16x8*)(As + row * 128 + ((ks * 64 + fg * 16) ^ ((row & 7) << 4)));
      }
#pragma unroll
      for (int j = 0; j < 4; ++j) {
        int row = wn * 64 + j * 16 + fr;
        bfr[j] = *(const bf16x8*)(Bs + row * 128 + ((ks * 64 + fg * 16) ^ ((row & 7) << 4)));
      }
#pragma unroll
      for (int i = 0; i < 4; ++i)
#pragma unroll
        for (int j = 0; j < 4; ++j) acc[i][j] = mfma16(af[i], bfr[j], acc[i][j]);
    }
    __syncthreads();
  }
  // epilogue
  if (widx < 3) {
    bf16* outf = (widx == 0) ? qf : (widx == 1) ? pf : kf_;
#pragma unroll
    for (int i = 0; i < 4; ++i)
#pragma unroll
      for (int j = 0; j < 4; ++j) {
        int n = n0 + wn * 64 + j * 16 + fr;
#pragma unroll
        for (int r = 0; r < 4; ++r) {
          int m = m0 + wm * 64 + i * 16 + fg * 4 + r;
          outf[(size_t)m * nD + n] = (bf16)acc[i][j][r];
        }
      }
  } else {
#pragma unroll
    for (int i = 0; i < 4; ++i)
#pragma unroll
      for (int j = 0; j < 4; ++j) {
        int n = n0 + wn * 64 + j * 16 + fr;
        int h = n >> 6, dk = n & 63;
        int mbase = m0 + wm * 64 + i * 16 + fg * 4;
        int b = mbase >> 11, s = mbase & (nS - 1);
        int bh = b * nH + h;
        bf16x4 pk;
#pragma unroll
        for (int r = 0; r < 4; ++r) pk[r] = (bf16)acc[i][j][r];
        *(bf16x4*)(vt + ((size_t)bh * nDK + dk) * nS + s) = pk;
      }
  }
}

// ---------------- attention pass 1 + leapfrog -> q_new (flat [4096][768] bf16) ----------------
__global__ __launch_bounds__(256) void k_attn(
    const bf16* __restrict__ qf, const bf16* __restrict__ pf,
    const bf16* __restrict__ kf_, const bf16* __restrict__ vt,
    const float* __restrict__ dtp, const float* __restrict__ gatep,
    bf16* __restrict__ qn) {
  __shared__ alignas(16) char pl[8192];  // 4 waves x [16][64] bf16 (swizzled)
  int t = threadIdx.x, lane = t & 63, w = t >> 6;
  int fr = lane & 15, fg = lane >> 4;
  int blk = blockIdx.x;
  int qt = blk & 31, bh = blk >> 5;
  int b = bh / nH, h = bh % nH;
  int q0 = qt * 64 + w * 16;
  const bf16* Qrow = qf + (size_t)(b * nS) * nD + (size_t)h * nDK;
  const bf16* Prow = pf + (size_t)(b * nS) * nD + (size_t)h * nDK;
  const bf16* Krow = kf_ + (size_t)(b * nS) * nD + (size_t)h * nDK;
  const bf16* Vb = vt + (size_t)bh * nDK * nS;
  char* myp = pl + w * 2048;

  bf16x8 qa[2];
#pragma unroll
  for (int ks = 0; ks < 2; ++ks)
    qa[ks] = *(const bf16x8*)(Qrow + (size_t)(q0 + fr) * nD + ks * 32 + fg * 8);

  float mr[4], lr[4];
  f32x4 o[4];
#pragma unroll
  for (int r = 0; r < 4; ++r) { mr[r] = -1e30f; lr[r] = 0.f; }
#pragma unroll
  for (int df = 0; df < 4; ++df) o[df] = (f32x4){0.f, 0.f, 0.f, 0.f};

  const float sc = 0.125f;  // DK^-0.5
  for (int kt = 0; kt < nS / 64; ++kt) {
    // S = Q K^T  (C-layout: row=q (fg*4+r), col=key (fr), 4 key-frags)
    f32x4 sf[4];
#pragma unroll
    for (int kfi = 0; kfi < 4; ++kfi) {
      int key = kt * 64 + kfi * 16 + fr;
      bf16x8 kb0 = *(const bf16x8*)(Krow + (size_t)key * nD + fg * 8);
      bf16x8 kb1 = *(const bf16x8*)(Krow + (size_t)key * nD + 32 + fg * 8);
      f32x4 sacc = (f32x4){0.f, 0.f, 0.f, 0.f};
      sacc = mfma16(qa[0], kb0, sacc);
      sacc = mfma16(qa[1], kb1, sacc);
      sf[kfi] = sacc;
    }
    // online softmax (row = q, reduce across fr lanes)
    float pv[4][4];
#pragma unroll
    for (int r = 0; r < 4; ++r) {
      float mx = fmaxf(fmaxf(sf[0][r], sf[1][r]), fmaxf(sf[2][r], sf[3][r]));
#pragma unroll
      for (int d = 1; d < 16; d <<= 1) mx = fmaxf(mx, __shfl_xor(mx, d));
      float mn = fmaxf(mr[r], mx * sc);
      float rs = __expf(mr[r] - mn);
      float ts = 0.f;
#pragma unroll
      for (int kfi = 0; kfi < 4; ++kfi) {
        float e = __expf(__builtin_fmaf(sf[kfi][r], sc, -mn));
        pv[kfi][r] = e;
        ts += e;
      }
#pragma unroll
      for (int d = 1; d < 16; d <<= 1) ts += __shfl_xor(ts, d);
      lr[r] = lr[r] * rs + ts;
      mr[r] = mn;
#pragma unroll
      for (int df = 0; df < 4; ++df) o[df][r] *= rs;
    }
    // P -> wave-private LDS (row-major [16 q][64 key] bf16, XOR-swizzled)
#pragma unroll
    for (int kfi = 0; kfi < 4; ++kfi)
#pragma unroll
      for (int r = 0; r < 4; ++r) {
        int row = fg * 4 + r;
        int colb = 2 * (fr + kfi * 16);
        *(bf16*)(myp + row * 128 + (colb ^ ((row & 7) << 4))) = (bf16)pv[kfi][r];
      }
    // O += P V   (A-frag: P[q=fr][t=fg*8+j], B-frag: V^T rows contiguous)
#pragma unroll
    for (int ks = 0; ks < 2; ++ks) {
      bf16x8 pa = *(const bf16x8*)(myp + fr * 128 + ((ks * 64 + fg * 16) ^ ((fr & 7) << 4)));
#pragma unroll
      for (int df = 0; df < 4; ++df) {
        bf16x8 vb = *(const bf16x8*)(Vb + (size_t)(df * 16 + fr) * nS + kt * 64 + ks * 32 + fg * 8);
        o[df] = mfma16(pa, vb, o[df]);
      }
    }
  }
  // leapfrog: q_new = q + dt*p - (dt^2/2)*gate*pe1
  float dt = dtp[0], gate = gatep[0];
  float c2 = 0.5f * dt * dt * gate;
#pragma unroll
  for (int df = 0; df < 4; ++df)
#pragma unroll
    for (int r = 0; r < 4; ++r) {
      int srow = q0 + fg * 4 + r;
      int dk = df * 16 + fr;
      float pe = o[df][r] / lr[r];
      float qv = (float)Qrow[(size_t)srow * nD + dk];
      float pp = (float)Prow[(size_t)srow * nD + dk];
      float qnv = qv + dt * pp - c2 * pe;
      qn[((size_t)(b * nS) + srow) * nD + h * nDK + dk] = (bf16)qnv;
    }
}

// ---------------- output GEMM: outp = qn @ Wo + bo + x (f32) ----------------
__global__ __launch_bounds__(256) void k_gemm_out(
    const bf16* __restrict__ qn, const bf16* __restrict__ wto,
    const float* __restrict__ bo, const float* __restrict__ x,
    float* __restrict__ outp) {
  __shared__ alignas(16) char smem[32768];
  char* As = smem;
  char* Bs = smem + 16384;
  int t = threadIdx.x, lane = t & 63, w = t >> 6;
  int fr = lane & 15, fg = lane >> 4;
  int wm = w >> 1, wn = w & 1;
  int m0 = blockIdx.y * 128, n0 = blockIdx.x * 128;
  int srow = t >> 3;
  int scol = (t & 7) * 8;

  f32x4 acc[4][4];
#pragma unroll
  for (int i = 0; i < 4; ++i)
#pragma unroll
    for (int j = 0; j < 4; ++j) acc[i][j] = (f32x4){0.f, 0.f, 0.f, 0.f};

  for (int kt = 0; kt < nD / 64; ++kt) {
    int k0 = kt * 64;
#pragma unroll
    for (int inst = 0; inst < 4; ++inst) {
      int row = inst * 32 + srow;
      int phys = row * 128 + (((t & 7) * 16) ^ ((row & 7) << 4));
      *(bf16x8*)(As + phys) = *(const bf16x8*)(qn + (size_t)(m0 + row) * nD + k0 + scol);
      *(bf16x8*)(Bs + phys) = *(const bf16x8*)(wto + (size_t)(n0 + row) * nD + k0 + scol);
    }
    __syncthreads();
#pragma unroll
    for (int ks = 0; ks < 2; ++ks) {
      bf16x8 af[4], bfr[4];
#pragma unroll
      for (int i = 0; i < 4; ++i) {
        int row = wm * 64 + i * 16 + fr;
        af[i] = *(const bf16x8*)(As + row * 128 + ((ks * 64 + fg * 16) ^ ((row & 7) << 4)));
      }
#pragma unroll
      for (int j = 0; j < 4; ++j) {
        int row = wn * 64 + j * 16 + fr;
        bfr[j] = *(const bf16x8*)(Bs + row * 128 + ((ks * 64 + fg * 16) ^ ((row & 7) << 4)));
      }
#pragma unroll
      for (int i = 0; i < 4; ++i)
#pragma unroll
        for (int j = 0; j < 4; ++j) acc[i][j] = mfma16(af[i], bfr[j], acc[i][j]);
    }
    __syncthreads();
  }
#pragma unroll
  for (int i = 0; i < 4; ++i)
#pragma unroll
    for (int j = 0; j < 4; ++j) {
      int n = n0 + wn * 64 + j * 16 + fr;
      float bias = bo[n];
#pragma unroll
      for (int r = 0; r < 4; ++r) {
        int m = m0 + wm * 64 + i * 16 + fg * 4 + r;
        outp[(size_t)m * nD + n] = acc[i][j][r] + bias + x[(size_t)m * nD + n];
      }
    }
}

// ---------------- LayerNorm (in-place on d_out), one wave per row ----------------
__global__ __launch_bounds__(256) void k_ln(const float* outp,
                                            const float* __restrict__ gamma,
                                            const float* __restrict__ beta,
                                            float* y) {
  int t = threadIdx.x, lane = t & 63, w = t >> 6;
  int row = blockIdx.x * 4 + w;
  const float* rp = outp + (size_t)row * nD;
  float v[12], s1 = 0.f, s2 = 0.f;
#pragma unroll
  for (int i = 0; i < 12; ++i) {
    v[i] = rp[lane + i * 64];
    s1 += v[i];
    s2 += v[i] * v[i];
  }
#pragma unroll
  for (int d = 1; d < 64; d <<= 1) {
    s1 += __shfl_xor(s1, d);
    s2 += __shfl_xor(s2, d);
  }
  float mu = s1 * (1.f / 768.f);
  float var = s2 * (1.f / 768.f) - mu * mu;
  float rstd = rsqrtf(var + LN_EPS);
  float* yp = y + (size_t)row * nD;
#pragma unroll
  for (int i = 0; i < 12; ++i) {
    int n = lane + i * 64;
    yp[n] = (v[i] - mu) * rstd * gamma[n] + beta[n];
  }
}

extern "C" void kernel_launch(void* const* d_in, const int* in_sizes, int n_in,
                              void* d_out, int out_size, void* d_ws, size_t ws_size,
                              hipStream_t stream) {
  const float* x = (const float*)d_in[0];
  const float* Wq = (const float*)d_in[1];
  const float* Wp = (const float*)d_in[2];
  const float* Wk = (const float*)d_in[3];
  const float* Wv = (const float*)d_in[4];
  const float* Wo = (const float*)d_in[5];
  const float* bo = (const float*)d_in[6];
  const float* gamma = (const float*)d_in[7];
  const float* beta = (const float*)d_in[8];
  const float* dt = (const float*)d_in[9];
  const float* gate = (const float*)d_in[10];

  char* ws = (char*)d_ws;
  const size_t szb = (size_t)nM * nD * 2;  // 6,291,456 bytes per bf16 [4096][768]
  bf16* xb = (bf16*)(ws + 0 * szb);        // reused as qn after QPKV GEMM
  bf16* qf = (bf16*)(ws + 1 * szb);
  bf16* pf = (bf16*)(ws + 2 * szb);
  bf16* kf_ = (bf16*)(ws + 3 * szb);
  bf16* vt = (bf16*)(ws + 4 * szb);
  bf16* wt = (bf16*)(ws + 5 * szb);  // 5 * 768*768 bf16 = 5,898,240 bytes
  bf16* qn = xb;
  float* outp = (float*)d_out;  // out-GEMM result, LN runs in place

  k_prep_x<<<dim3(nM * nD / 1024), dim3(256), 0, stream>>>(x, xb);
  k_prep_w<<<dim3(12, 12, 5), dim3(256), 0, stream>>>(Wq, Wp, Wk, Wv, Wo, wt);
  k_gemm_qpkv<<<dim3(6, 32, 4), dim3(256), 0, stream>>>(xb, wt, qf, pf, kf_, vt);
  k_attn<<<dim3(768), dim3(256), 0, stream>>>(qf, pf, kf_, vt, dt, gate, qn);
  k_gemm_out<<<dim3(6, 32), dim3(256), 0, stream>>>(qn, wt + 4 * (size_t)nD * nD, bo, x, outp);
  k_ln<<<dim3(nM / 4), dim3(256), 0, stream>>>(outp, gamma, beta, (float*)d_out);
}

// Round 2
// 239.615 us; speedup vs baseline: 1.0342x; 1.0342x over previous
//
#include <hip/hip_runtime.h>
#include <stdint.h>

typedef __bf16 bf16;
typedef __bf16 bf16x8 __attribute__((ext_vector_type(8)));
typedef __bf16 bf16x4 __attribute__((ext_vector_type(4)));
typedef float f32x4 __attribute__((ext_vector_type(4)));

constexpr int nB = 2, nS = 2048, nD = 768, nH = 12, nDK = 64;
constexpr int nM = nB * nS;  // 4096
constexpr float LN_EPS = 1e-5f;

static __device__ __forceinline__ f32x4 mfma16(bf16x8 a, bf16x8 b, f32x4 c) {
  return __builtin_amdgcn_mfma_f32_16x16x32_bf16(a, b, c, 0, 0, 0);
}

// ---------------- prep: x -> bf16 ----------------
__global__ __launch_bounds__(256) void k_prep_x(const float* __restrict__ x,
                                                bf16* __restrict__ xb) {
  int i = (blockIdx.x * 256 + threadIdx.x) * 4;
  float4 v = *(const float4*)(x + i);
  bf16x4 o;
  o[0] = (bf16)v.x; o[1] = (bf16)v.y; o[2] = (bf16)v.z; o[3] = (bf16)v.w;
  *(bf16x4*)(xb + i) = o;
}

// ---------------- prep: weights -> bf16, transposed to [n][k] ----------------
__global__ __launch_bounds__(256) void k_prep_w(
    const float* __restrict__ w0, const float* __restrict__ w1,
    const float* __restrict__ w2, const float* __restrict__ w3,
    const float* __restrict__ w4, bf16* __restrict__ wt) {
  __shared__ float tb[64][65];
  int w = blockIdx.z;
  const float* src = (w == 0) ? w0 : (w == 1) ? w1 : (w == 2) ? w2 : (w == 3) ? w3 : w4;
  int k0 = blockIdx.y * 64, n0 = blockIdx.x * 64;
  int tx = threadIdx.x & 63, ty = threadIdx.x >> 6;
#pragma unroll
  for (int it = 0; it < 16; ++it) {
    int r = it * 4 + ty;
    tb[r][tx] = src[(size_t)(k0 + r) * nD + n0 + tx];
  }
  __syncthreads();
  bf16* dst = wt + (size_t)w * nD * nD;
#pragma unroll
  for (int it = 0; it < 16; ++it) {
    int r = it * 4 + ty;
    dst[(size_t)(n0 + r) * nD + k0 + tx] = (bf16)tb[tx][r];
  }
}

// ---------------- QPKV GEMM: C = X @ W (Wt is W^T), 128x128 tile, BK=64 ----------------
// z = 0..3 selects {Wq->qf, Wp->pf, Wk->kf, Wv->vt(transposed layout)}
__global__ __launch_bounds__(256) void k_gemm_qpkv(
    const bf16* __restrict__ xb, const bf16* __restrict__ wt,
    bf16* __restrict__ qf, bf16* __restrict__ pf, bf16* __restrict__ kf_,
    bf16* __restrict__ vt) {
  __shared__ alignas(16) char smem[32768];
  char* As = smem;
  char* Bs = smem + 16384;
  int t = threadIdx.x, lane = t & 63, w = t >> 6;
  int fr = lane & 15, fg = lane >> 4;
  int wm = w >> 1, wn = w & 1;
  int widx = blockIdx.z;
  int m0 = blockIdx.y * 128, n0 = blockIdx.x * 128;
  const bf16* wbase = wt + (size_t)widx * nD * nD;
  int srow = t >> 3;       // 0..31 (row within 32-row staging slab)
  int scol = (t & 7) * 8;  // element col 0..56

  f32x4 acc[4][4];
#pragma unroll
  for (int i = 0; i < 4; ++i)
#pragma unroll
    for (int j = 0; j < 4; ++j) acc[i][j] = (f32x4){0.f, 0.f, 0.f, 0.f};

  for (int kt = 0; kt < nD / 64; ++kt) {
    int k0 = kt * 64;
#pragma unroll
    for (int inst = 0; inst < 4; ++inst) {
      int row = inst * 32 + srow;
      int phys = row * 128 + (((t & 7) * 16) ^ ((row & 7) << 4));
      *(bf16x8*)(As + phys) = *(const bf16x8*)(xb + (size_t)(m0 + row) * nD + k0 + scol);
      *(bf16x8*)(Bs + phys) = *(const bf16x8*)(wbase + (size_t)(n0 + row) * nD + k0 + scol);
    }
    __syncthreads();
#pragma unroll
    for (int ks = 0; ks < 2; ++ks) {
      bf16x8 af[4], bfr[4];
#pragma unroll
      for (int i = 0; i < 4; ++i) {
        int row = wm * 64 + i * 16 + fr;
        af[i] = *(const bf16x8*)(As + row * 128 + ((ks * 64 + fg * 16) ^ ((row & 7) << 4)));
      }
#pragma unroll
      for (int j = 0; j < 4; ++j) {
        int row = wn * 64 + j * 16 + fr;
        bfr[j] = *(const bf16x8*)(Bs + row * 128 + ((ks * 64 + fg * 16) ^ ((row & 7) << 4)));
      }
#pragma unroll
      for (int i = 0; i < 4; ++i)
#pragma unroll
        for (int j = 0; j < 4; ++j) acc[i][j] = mfma16(af[i], bfr[j], acc[i][j]);
    }
    __syncthreads();
  }
  // epilogue
  if (widx < 3) {
    bf16* outf = (widx == 0) ? qf : (widx == 1) ? pf : kf_;
#pragma unroll
    for (int i = 0; i < 4; ++i)
#pragma unroll
      for (int j = 0; j < 4; ++j) {
        int n = n0 + wn * 64 + j * 16 + fr;
#pragma unroll
        for (int r = 0; r < 4; ++r) {
          int m = m0 + wm * 64 + i * 16 + fg * 4 + r;
          outf[(size_t)m * nD + n] = (bf16)acc[i][j][r];
        }
      }
  } else {
#pragma unroll
    for (int i = 0; i < 4; ++i)
#pragma unroll
      for (int j = 0; j < 4; ++j) {
        int n = n0 + wn * 64 + j * 16 + fr;
        int h = n >> 6, dk = n & 63;
        int mbase = m0 + wm * 64 + i * 16 + fg * 4;
        int b = mbase >> 11, s = mbase & (nS - 1);
        int bh = b * nH + h;
        bf16x4 pk;
#pragma unroll
        for (int r = 0; r < 4; ++r) pk[r] = (bf16)acc[i][j][r];
        *(bf16x4*)(vt + ((size_t)bh * nDK + dk) * nS + s) = pk;
      }
  }
}

// ---------------- attention pass 1 + leapfrog -> q_new (flat [4096][768] bf16) ----------------
// Swapped-QK^T structure: S^T = mfma(K_frag, Q_frag) so each lane owns all
// scores of one q-row (q = lane&15). Softmax: 16 local values + 2 shfl_xor
// (over lane bits 4,5). O accumulated transposed: O^T = mfma(V^T_frag, P^T_frag).
__global__ __launch_bounds__(256) void k_attn(
    const bf16* __restrict__ qf, const bf16* __restrict__ pf,
    const bf16* __restrict__ kf_, const bf16* __restrict__ vt,
    const float* __restrict__ dtp, const float* __restrict__ gatep,
    bf16* __restrict__ qn) {
  __shared__ alignas(16) char pl[8192];  // 4 waves x [16 q][64 key] bf16 (swizzled)
  int t = threadIdx.x, lane = t & 63, w = t >> 6;
  int fr = lane & 15, fg = lane >> 4;
  int blk = blockIdx.x;
  int qt = blk & 31, bh = blk >> 5;
  int b = bh / nH, h = bh % nH;
  int q0 = qt * 64 + w * 16;
  const bf16* Qrow = qf + (size_t)(b * nS) * nD + (size_t)h * nDK;
  const bf16* Prow = pf + (size_t)(b * nS) * nD + (size_t)h * nDK;
  const bf16* Krow = kf_ + (size_t)(b * nS) * nD + (size_t)h * nDK;
  const bf16* Vb = vt + (size_t)bh * nDK * nS;
  char* myp = pl + w * 2048;

  // Q fragment (B operand): lane.fr = q, k-chunk = fg*8..fg*8+7 (+32 for half 1)
  bf16x8 qa[2];
#pragma unroll
  for (int ks = 0; ks < 2; ++ks)
    qa[ks] = *(const bf16x8*)(Qrow + (size_t)(q0 + fr) * nD + ks * 32 + fg * 8);

  float mr = -1e30f, lr = 0.f;  // per-lane running max/sum for q = q0+fr
  f32x4 o[4];                   // O^T[dv = df*16 + fg*4 + r][q = fr]
#pragma unroll
  for (int df = 0; df < 4; ++df) o[df] = (f32x4){0.f, 0.f, 0.f, 0.f};

  const float sc = 0.125f;  // DK^-0.5
  for (int kt = 0; kt < nS / 64; ++kt) {
    // S^T = K Q^T: lane gets S[q=fr][key = kt*64 + kfi*16 + fg*4 + r]
    f32x4 sf[4];
#pragma unroll
    for (int kfi = 0; kfi < 4; ++kfi) {
      int key = kt * 64 + kfi * 16 + fr;
      bf16x8 kb0 = *(const bf16x8*)(Krow + (size_t)key * nD + fg * 8);
      bf16x8 kb1 = *(const bf16x8*)(Krow + (size_t)key * nD + 32 + fg * 8);
      f32x4 sacc = mfma16(kb0, qa[0], (f32x4){0.f, 0.f, 0.f, 0.f});
      sf[kfi] = mfma16(kb1, qa[1], sacc);
    }
    // online softmax: all 64 tile-keys for q=fr live in the 4 lanes sharing fr
    float mx = -1e30f;
#pragma unroll
    for (int kfi = 0; kfi < 4; ++kfi)
#pragma unroll
      for (int r = 0; r < 4; ++r) mx = fmaxf(mx, sf[kfi][r]);
    mx = fmaxf(mx, __shfl_xor(mx, 16));
    mx = fmaxf(mx, __shfl_xor(mx, 32));
    float mn = fmaxf(mr, mx * sc);
    float rs = __expf(mr - mn);
    float e[4][4];
    float ts = 0.f;
#pragma unroll
    for (int kfi = 0; kfi < 4; ++kfi)
#pragma unroll
      for (int r = 0; r < 4; ++r) {
        float v = __expf(__builtin_fmaf(sf[kfi][r], sc, -mn));
        e[kfi][r] = v;
        ts += v;
      }
    ts += __shfl_xor(ts, 16);
    ts += __shfl_xor(ts, 32);
    lr = lr * rs + ts;
    mr = mn;
#pragma unroll
    for (int df = 0; df < 4; ++df) o[df] *= rs;
    // P^T -> wave-private LDS [16 q][64 key] bf16, 16B-block XOR swizzle by (q&7)
#pragma unroll
    for (int kfi = 0; kfi < 4; ++kfi) {
      bf16x4 pk;
#pragma unroll
      for (int r = 0; r < 4; ++r) pk[r] = (bf16)e[kfi][r];
      int blk16 = kfi * 2 + (fg >> 1);
      int phys = fr * 128 + (((blk16 ^ (fr & 7)) << 4) | ((fg & 1) << 3));
      *(bf16x4*)(myp + phys) = pk;
    }
    // O^T += V^T P^T
#pragma unroll
    for (int ks = 0; ks < 2; ++ks) {
      bf16x8 pb = *(const bf16x8*)(myp + fr * 128 + (((ks * 4 + fg) ^ (fr & 7)) << 4));
#pragma unroll
      for (int df = 0; df < 4; ++df) {
        bf16x8 vb = *(const bf16x8*)(Vb + (size_t)(df * 16 + fr) * nS + kt * 64 + ks * 32 + fg * 8);
        o[df] = mfma16(vb, pb, o[df]);
      }
    }
  }
  // leapfrog: q_new = q + dt*p - (dt^2/2)*gate*pe1
  float dt = dtp[0], gate = gatep[0];
  float c2 = 0.5f * dt * dt * gate;
  float inv = 1.f / lr;
  int qrow = q0 + fr;
#pragma unroll
  for (int df = 0; df < 4; ++df) {
    int dk = df * 16 + fg * 4;
    bf16x4 qv4 = *(const bf16x4*)(Qrow + (size_t)qrow * nD + dk);
    bf16x4 pv4 = *(const bf16x4*)(Prow + (size_t)qrow * nD + dk);
    bf16x4 ov;
#pragma unroll
    for (int r = 0; r < 4; ++r) {
      float pe = o[df][r] * inv;
      ov[r] = (bf16)((float)qv4[r] + dt * (float)pv4[r] - c2 * pe);
    }
    *(bf16x4*)(qn + ((size_t)(b * nS) + qrow) * nD + h * nDK + dk) = ov;
  }
}

// ---------------- output GEMM: outp = qn @ Wo + bo + x (f32) ----------------
__global__ __launch_bounds__(256) void k_gemm_out(
    const bf16* __restrict__ qn, const bf16* __restrict__ wto,
    const float* __restrict__ bo, const float* __restrict__ x,
    float* __restrict__ outp) {
  __shared__ alignas(16) char smem[32768];
  char* As = smem;
  char* Bs = smem + 16384;
  int t = threadIdx.x, lane = t & 63, w = t >> 6;
  int fr = lane & 15, fg = lane >> 4;
  int wm = w >> 1, wn = w & 1;
  int m0 = blockIdx.y * 128, n0 = blockIdx.x * 128;
  int srow = t >> 3;
  int scol = (t & 7) * 8;

  f32x4 acc[4][4];
#pragma unroll
  for (int i = 0; i < 4; ++i)
#pragma unroll
    for (int j = 0; j < 4; ++j) acc[i][j] = (f32x4){0.f, 0.f, 0.f, 0.f};

  for (int kt = 0; kt < nD / 64; ++kt) {
    int k0 = kt * 64;
#pragma unroll
    for (int inst = 0; inst < 4; ++inst) {
      int row = inst * 32 + srow;
      int phys = row * 128 + (((t & 7) * 16) ^ ((row & 7) << 4));
      *(bf16x8*)(As + phys) = *(const bf16x8*)(qn + (size_t)(m0 + row) * nD + k0 + scol);
      *(bf16x8*)(Bs + phys) = *(const bf16x8*)(wto + (size_t)(n0 + row) * nD + k0 + scol);
    }
    __syncthreads();
#pragma unroll
    for (int ks = 0; ks < 2; ++ks) {
      bf16x8 af[4], bfr[4];
#pragma unroll
      for (int i = 0; i < 4; ++i) {
        int row = wm * 64 + i * 16 + fr;
        af[i] = *(const bf16x8*)(As + row * 128 + ((ks * 64 + fg * 16) ^ ((row & 7) << 4)));
      }
#pragma unroll
      for (int j = 0; j < 4; ++j) {
        int row = wn * 64 + j * 16 + fr;
        bfr[j] = *(const bf16x8*)(Bs + row * 128 + ((ks * 64 + fg * 16) ^ ((row & 7) << 4)));
      }
#pragma unroll
      for (int i = 0; i < 4; ++i)
#pragma unroll
        for (int j = 0; j < 4; ++j) acc[i][j] = mfma16(af[i], bfr[j], acc[i][j]);
    }
    __syncthreads();
  }
#pragma unroll
  for (int i = 0; i < 4; ++i)
#pragma unroll
    for (int j = 0; j < 4; ++j) {
      int n = n0 + wn * 64 + j * 16 + fr;
      float bias = bo[n];
#pragma unroll
      for (int r = 0; r < 4; ++r) {
        int m = m0 + wm * 64 + i * 16 + fg * 4 + r;
        outp[(size_t)m * nD + n] = acc[i][j][r] + bias + x[(size_t)m * nD + n];
      }
    }
}

// ---------------- LayerNorm (in-place on d_out), one wave per row ----------------
__global__ __launch_bounds__(256) void k_ln(const float* outp,
                                            const float* __restrict__ gamma,
                                            const float* __restrict__ beta,
                                            float* y) {
  int t = threadIdx.x, lane = t & 63, w = t >> 6;
  int row = blockIdx.x * 4 + w;
  const float* rp = outp + (size_t)row * nD;
  float v[12], s1 = 0.f, s2 = 0.f;
#pragma unroll
  for (int i = 0; i < 12; ++i) {
    v[i] = rp[lane + i * 64];
    s1 += v[i];
    s2 += v[i] * v[i];
  }
#pragma unroll
  for (int d = 1; d < 64; d <<= 1) {
    s1 += __shfl_xor(s1, d);
    s2 += __shfl_xor(s2, d);
  }
  float mu = s1 * (1.f / 768.f);
  float var = s2 * (1.f / 768.f) - mu * mu;
  float rstd = rsqrtf(var + LN_EPS);
  float* yp = y + (size_t)row * nD;
#pragma unroll
  for (int i = 0; i < 12; ++i) {
    int n = lane + i * 64;
    yp[n] = (v[i] - mu) * rstd * gamma[n] + beta[n];
  }
}

extern "C" void kernel_launch(void* const* d_in, const int* in_sizes, int n_in,
                              void* d_out, int out_size, void* d_ws, size_t ws_size,
                              hipStream_t stream) {
  const float* x = (const float*)d_in[0];
  const float* Wq = (const float*)d_in[1];
  const float* Wp = (const float*)d_in[2];
  const float* Wk = (const float*)d_in[3];
  const float* Wv = (const float*)d_in[4];
  const float* Wo = (const float*)d_in[5];
  const float* bo = (const float*)d_in[6];
  const float* gamma = (const float*)d_in[7];
  const float* beta = (const float*)d_in[8];
  const float* dt = (const float*)d_in[9];
  const float* gate = (const float*)d_in[10];

  char* ws = (char*)d_ws;
  const size_t szb = (size_t)nM * nD * 2;  // 6,291,456 bytes per bf16 [4096][768]
  bf16* xb = (bf16*)(ws + 0 * szb);        // reused as qn after QPKV GEMM
  bf16* qf = (bf16*)(ws + 1 * szb);
  bf16* pf = (bf16*)(ws + 2 * szb);
  bf16* kf_ = (bf16*)(ws + 3 * szb);
  bf16* vt = (bf16*)(ws + 4 * szb);
  bf16* wt = (bf16*)(ws + 5 * szb);  // 5 * 768*768 bf16 = 5,898,240 bytes
  bf16* qn = xb;
  float* outp = (float*)d_out;  // out-GEMM result, LN runs in place

  k_prep_x<<<dim3(nM * nD / 1024), dim3(256), 0, stream>>>(x, xb);
  k_prep_w<<<dim3(12, 12, 5), dim3(256), 0, stream>>>(Wq, Wp, Wk, Wv, Wo, wt);
  k_gemm_qpkv<<<dim3(6, 32, 4), dim3(256), 0, stream>>>(xb, wt, qf, pf, kf_, vt);
  k_attn<<<dim3(768), dim3(256), 0, stream>>>(qf, pf, kf_, vt, dt, gate, qn);
  k_gemm_out<<<dim3(6, 32), dim3(256), 0, stream>>>(qn, wt + 4 * (size_t)nD * nD, bo, x, outp);
  k_ln<<<dim3(nM / 4), dim3(256), 0, stream>>>(outp, gamma, beta, (float*)d_out);
}

// Round 3
// 124.278 us; speedup vs baseline: 1.9939x; 1.9281x over previous
//
#include <hip/hip_runtime.h>
#include <stdint.h>

typedef __bf16 bf16;
typedef __bf16 bf16x8 __attribute__((ext_vector_type(8)));
typedef __bf16 bf16x4 __attribute__((ext_vector_type(4)));
typedef float f32x4 __attribute__((ext_vector_type(4)));

constexpr int nB = 2, nS = 2048, nD = 768, nH = 12, nDK = 64;
constexpr int nM = nB * nS;  // 4096
constexpr float LN_EPS = 1e-5f;

static __device__ __forceinline__ f32x4 mfma16(bf16x8 a, bf16x8 b, f32x4 c) {
  return __builtin_amdgcn_mfma_f32_16x16x32_bf16(a, b, c, 0, 0, 0);
}

static __device__ __forceinline__ void gll16(const void* g, void* l) {
  __builtin_amdgcn_global_load_lds(
      (const __attribute__((address_space(1))) void*)g,
      (__attribute__((address_space(3))) void*)l, 16, 0, 0);
}

// ---------------- prep: x -> bf16 ----------------
__global__ __launch_bounds__(256) void k_prep_x(const float* __restrict__ x,
                                                bf16* __restrict__ xb) {
  int i = (blockIdx.x * 256 + threadIdx.x) * 4;
  float4 v = *(const float4*)(x + i);
  bf16x4 o;
  o[0] = (bf16)v.x; o[1] = (bf16)v.y; o[2] = (bf16)v.z; o[3] = (bf16)v.w;
  *(bf16x4*)(xb + i) = o;
}

// ---------------- prep: weights -> bf16, transposed to [n][k] ----------------
__global__ __launch_bounds__(256) void k_prep_w(
    const float* __restrict__ w0, const float* __restrict__ w1,
    const float* __restrict__ w2, const float* __restrict__ w3,
    const float* __restrict__ w4, bf16* __restrict__ wt) {
  __shared__ float tb[64][65];
  int w = blockIdx.z;
  const float* src = (w == 0) ? w0 : (w == 1) ? w1 : (w == 2) ? w2 : (w == 3) ? w3 : w4;
  int k0 = blockIdx.y * 64, n0 = blockIdx.x * 64;
  int tx = threadIdx.x & 63, ty = threadIdx.x >> 6;
#pragma unroll
  for (int it = 0; it < 16; ++it) {
    int r = it * 4 + ty;
    tb[r][tx] = src[(size_t)(k0 + r) * nD + n0 + tx];
  }
  __syncthreads();
  bf16* dst = wt + (size_t)w * nD * nD;
#pragma unroll
  for (int it = 0; it < 16; ++it) {
    int r = it * 4 + ty;
    dst[(size_t)(n0 + r) * nD + k0 + tx] = (bf16)tb[tx][r];
  }
}

// ---------------- QPKV GEMM: C = X @ W (Wt is W^T), 128x128 tile, BK=64 ----------------
__global__ __launch_bounds__(256) void k_gemm_qpkv(
    const bf16* __restrict__ xb, const bf16* __restrict__ wt,
    bf16* __restrict__ qf, bf16* __restrict__ pf, bf16* __restrict__ kf_,
    bf16* __restrict__ vt) {
  __shared__ alignas(16) char smem[32768];
  char* As = smem;
  char* Bs = smem + 16384;
  int t = threadIdx.x, lane = t & 63, w = t >> 6;
  int fr = lane & 15, fg = lane >> 4;
  int wm = w >> 1, wn = w & 1;
  int widx = blockIdx.z;
  int m0 = blockIdx.y * 128, n0 = blockIdx.x * 128;
  const bf16* wbase = wt + (size_t)widx * nD * nD;
  int srow = t >> 3;       // 0..31 (row within 32-row staging slab)
  int scol = (t & 7) * 8;  // element col 0..56

  f32x4 acc[4][4];
#pragma unroll
  for (int i = 0; i < 4; ++i)
#pragma unroll
    for (int j = 0; j < 4; ++j) acc[i][j] = (f32x4){0.f, 0.f, 0.f, 0.f};

  for (int kt = 0; kt < nD / 64; ++kt) {
    int k0 = kt * 64;
#pragma unroll
    for (int inst = 0; inst < 4; ++inst) {
      int row = inst * 32 + srow;
      int phys = row * 128 + (((t & 7) * 16) ^ ((row & 7) << 4));
      *(bf16x8*)(As + phys) = *(const bf16x8*)(xb + (size_t)(m0 + row) * nD + k0 + scol);
      *(bf16x8*)(Bs + phys) = *(const bf16x8*)(wbase + (size_t)(n0 + row) * nD + k0 + scol);
    }
    __syncthreads();
#pragma unroll
    for (int ks = 0; ks < 2; ++ks) {
      bf16x8 af[4], bfr[4];
#pragma unroll
      for (int i = 0; i < 4; ++i) {
        int row = wm * 64 + i * 16 + fr;
        af[i] = *(const bf16x8*)(As + row * 128 + ((ks * 64 + fg * 16) ^ ((row & 7) << 4)));
      }
#pragma unroll
      for (int j = 0; j < 4; ++j) {
        int row = wn * 64 + j * 16 + fr;
        bfr[j] = *(const bf16x8*)(Bs + row * 128 + ((ks * 64 + fg * 16) ^ ((row & 7) << 4)));
      }
#pragma unroll
      for (int i = 0; i < 4; ++i)
#pragma unroll
        for (int j = 0; j < 4; ++j) acc[i][j] = mfma16(af[i], bfr[j], acc[i][j]);
    }
    __syncthreads();
  }
  // epilogue
  if (widx < 3) {
    bf16* outf = (widx == 0) ? qf : (widx == 1) ? pf : kf_;
#pragma unroll
    for (int i = 0; i < 4; ++i)
#pragma unroll
      for (int j = 0; j < 4; ++j) {
        int n = n0 + wn * 64 + j * 16 + fr;
#pragma unroll
        for (int r = 0; r < 4; ++r) {
          int m = m0 + wm * 64 + i * 16 + fg * 4 + r;
          outf[(size_t)m * nD + n] = (bf16)acc[i][j][r];
        }
      }
  } else {
#pragma unroll
    for (int i = 0; i < 4; ++i)
#pragma unroll
      for (int j = 0; j < 4; ++j) {
        int n = n0 + wn * 64 + j * 16 + fr;
        int h = n >> 6, dk = n & 63;
        int mbase = m0 + wm * 64 + i * 16 + fg * 4;
        int b = mbase >> 11, s = mbase & (nS - 1);
        int bh = b * nH + h;
        bf16x4 pk;
#pragma unroll
        for (int r = 0; r < 4; ++r) pk[r] = (bf16)acc[i][j][r];
        *(bf16x4*)(vt + ((size_t)bh * nDK + dk) * nS + s) = pk;
      }
  }
}

// ---------------- attention pass 1 + leapfrog -> q_new (flat [4096][768] bf16) ----------------
// Swapped-QK^T (each lane owns one q-row's scores) + LDS-staged K/V tiles:
// double-buffered global_load_lds(16B) shared by all 4 waves, 2-phase schedule.
__global__ __launch_bounds__(256) void k_attn(
    const bf16* __restrict__ qf, const bf16* __restrict__ pf,
    const bf16* __restrict__ kf_, const bf16* __restrict__ vt,
    const float* __restrict__ dtp, const float* __restrict__ gatep,
    bf16* __restrict__ qn) {
  // LDS: K dbuf 2x8KB | V dbuf 2x8KB | P 4x2KB  = 40KB
  __shared__ alignas(16) char lds[40960];
  char* kb0_ = lds;
  char* kb1_ = lds + 8192;
  char* vb0_ = lds + 16384;
  char* vb1_ = lds + 24576;
  char* plbase = lds + 32768;

  int t = threadIdx.x, lane = t & 63, w = t >> 6;
  int fr = lane & 15, fg = lane >> 4;
  int blk = blockIdx.x;
  int qt = blk & 31, bh = blk >> 5;
  int b = bh / nH, h = bh % nH;
  int q0 = qt * 64 + w * 16;
  const bf16* Qrow = qf + (size_t)(b * nS) * nD + (size_t)h * nDK;
  const bf16* Prow = pf + (size_t)(b * nS) * nD + (size_t)h * nDK;
  const bf16* Krow = kf_ + (size_t)(b * nS) * nD + (size_t)h * nDK;
  const bf16* Vb = vt + (size_t)bh * nDK * nS;
  char* myp = plbase + w * 2048;

  // Q fragment (B operand): lane.fr = q, k-chunk = fg*8 (+32 for half 1)
  bf16x8 qa[2];
#pragma unroll
  for (int ks = 0; ks < 2; ++ks)
    qa[ks] = *(const bf16x8*)(Qrow + (size_t)(q0 + fr) * nD + ks * 32 + fg * 8);

  float mr = -1e30f, lr = 0.f;
  f32x4 o[4];  // O^T[dv = df*16 + fg*4 + r][q = fr]
#pragma unroll
  for (int df = 0; df < 4; ++df) o[df] = (f32x4){0.f, 0.f, 0.f, 0.f};

  const float sc = 0.125f;  // DK^-0.5
  int rsub = lane >> 3, cir = lane & 7;

  // stage K/V tile kt into (bK,bV); rows split: wave w stages rows [w*16,w*16+16)
  // LDS linear [row][chunk], 16B chunks; swizzle on READ side: phys_c = c ^ (row&7),
  // so SOURCE address uses c_logical = cir ^ (row&7) (involution).
#define STAGE(bK, bV, kt)                                                      \
  {                                                                            \
    _Pragma("unroll") for (int i = 0; i < 2; ++i) {                            \
      int row = w * 16 + i * 8 + rsub;                                         \
      int c = cir ^ (row & 7);                                                 \
      gll16(Krow + (size_t)((kt)*64 + row) * nD + c * 8,                       \
            (bK) + w * 2048 + i * 1024);                                       \
      gll16(Vb + (size_t)row * nS + (kt)*64 + c * 8,                           \
            (bV) + w * 2048 + i * 1024);                                       \
    }                                                                          \
  }

#define COMPUTE(bK, bV)                                                        \
  {                                                                            \
    f32x4 sf[4];                                                               \
    _Pragma("unroll") for (int kfi = 0; kfi < 4; ++kfi) {                      \
      int key = kfi * 16 + fr;                                                 \
      bf16x8 ka = *(const bf16x8*)((bK) + key * 128 + ((fg ^ (key & 7)) << 4));\
      bf16x8 kc =                                                              \
          *(const bf16x8*)((bK) + key * 128 + (((4 + fg) ^ (key & 7)) << 4));  \
      f32x4 sacc = mfma16(ka, qa[0], (f32x4){0.f, 0.f, 0.f, 0.f});             \
      sf[kfi] = mfma16(kc, qa[1], sacc);                                       \
    }                                                                          \
    float mx = -1e30f;                                                         \
    _Pragma("unroll") for (int kfi = 0; kfi < 4; ++kfi)                        \
        _Pragma("unroll") for (int r = 0; r < 4; ++r) mx =                     \
        fmaxf(mx, sf[kfi][r]);                                                 \
    mx = fmaxf(mx, __shfl_xor(mx, 16));                                        \
    mx = fmaxf(mx, __shfl_xor(mx, 32));                                        \
    float mn = fmaxf(mr, mx * sc);                                             \
    float rs = __expf(mr - mn);                                                \
    float e[4][4];                                                             \
    float ts = 0.f;                                                            \
    _Pragma("unroll") for (int kfi = 0; kfi < 4; ++kfi)                        \
        _Pragma("unroll") for (int r = 0; r < 4; ++r) {                        \
      float v = __expf(__builtin_fmaf(sf[kfi][r], sc, -mn));                   \
      e[kfi][r] = v;                                                           \
      ts += v;                                                                 \
    }                                                                          \
    ts += __shfl_xor(ts, 16);                                                  \
    ts += __shfl_xor(ts, 32);                                                  \
    lr = lr * rs + ts;                                                         \
    mr = mn;                                                                   \
    _Pragma("unroll") for (int df = 0; df < 4; ++df) o[df] *= rs;              \
    _Pragma("unroll") for (int kfi = 0; kfi < 4; ++kfi) {                      \
      bf16x4 pk;                                                               \
      _Pragma("unroll") for (int r = 0; r < 4; ++r) pk[r] = (bf16)e[kfi][r];   \
      int blk16 = kfi * 2 + (fg >> 1);                                         \
      int phys = fr * 128 + (((blk16 ^ (fr & 7)) << 4) | ((fg & 1) << 3));     \
      *(bf16x4*)(myp + phys) = pk;                                             \
    }                                                                          \
    _Pragma("unroll") for (int ks = 0; ks < 2; ++ks) {                         \
      bf16x8 pb =                                                              \
          *(const bf16x8*)(myp + fr * 128 + (((ks * 4 + fg) ^ (fr & 7)) << 4));\
      _Pragma("unroll") for (int df = 0; df < 4; ++df) {                       \
        int row = df * 16 + fr;                                                \
        bf16x8 vv = *(const bf16x8*)((bV) + row * 128 +                        \
                                     (((ks * 4 + fg) ^ (row & 7)) << 4));      \
        o[df] = mfma16(vv, pb, o[df]);                                         \
      }                                                                        \
    }                                                                          \
  }

  STAGE(kb0_, vb0_, 0);
  __syncthreads();
#pragma unroll 1
  for (int kt = 0; kt < 32; kt += 2) {
    STAGE(kb1_, vb1_, kt + 1);
    COMPUTE(kb0_, vb0_);
    __syncthreads();
    if (kt + 2 < 32) STAGE(kb0_, vb0_, kt + 2);
    COMPUTE(kb1_, vb1_);
    __syncthreads();
  }
#undef STAGE
#undef COMPUTE

  // leapfrog: q_new = q + dt*p - (dt^2/2)*gate*pe1
  float dt = dtp[0], gate = gatep[0];
  float c2 = 0.5f * dt * dt * gate;
  float inv = 1.f / lr;
  int qrow = q0 + fr;
#pragma unroll
  for (int df = 0; df < 4; ++df) {
    int dk = df * 16 + fg * 4;
    bf16x4 qv4 = *(const bf16x4*)(Qrow + (size_t)qrow * nD + dk);
    bf16x4 pv4 = *(const bf16x4*)(Prow + (size_t)qrow * nD + dk);
    bf16x4 ov;
#pragma unroll
    for (int r = 0; r < 4; ++r) {
      float pe = o[df][r] * inv;
      ov[r] = (bf16)((float)qv4[r] + dt * (float)pv4[r] - c2 * pe);
    }
    *(bf16x4*)(qn + ((size_t)(b * nS) + qrow) * nD + h * nDK + dk) = ov;
  }
}

// ---------------- output GEMM: outp = qn @ Wo + bo + x (f32) ----------------
__global__ __launch_bounds__(256) void k_gemm_out(
    const bf16* __restrict__ qn, const bf16* __restrict__ wto,
    const float* __restrict__ bo, const float* __restrict__ x,
    float* __restrict__ outp) {
  __shared__ alignas(16) char smem[32768];
  char* As = smem;
  char* Bs = smem + 16384;
  int t = threadIdx.x, lane = t & 63, w = t >> 6;
  int fr = lane & 15, fg = lane >> 4;
  int wm = w >> 1, wn = w & 1;
  int m0 = blockIdx.y * 128, n0 = blockIdx.x * 128;
  int srow = t >> 3;
  int scol = (t & 7) * 8;

  f32x4 acc[4][4];
#pragma unroll
  for (int i = 0; i < 4; ++i)
#pragma unroll
    for (int j = 0; j < 4; ++j) acc[i][j] = (f32x4){0.f, 0.f, 0.f, 0.f};

  for (int kt = 0; kt < nD / 64; ++kt) {
    int k0 = kt * 64;
#pragma unroll
    for (int inst = 0; inst < 4; ++inst) {
      int row = inst * 32 + srow;
      int phys = row * 128 + (((t & 7) * 16) ^ ((row & 7) << 4));
      *(bf16x8*)(As + phys) = *(const bf16x8*)(qn + (size_t)(m0 + row) * nD + k0 + scol);
      *(bf16x8*)(Bs + phys) = *(const bf16x8*)(wto + (size_t)(n0 + row) * nD + k0 + scol);
    }
    __syncthreads();
#pragma unroll
    for (int ks = 0; ks < 2; ++ks) {
      bf16x8 af[4], bfr[4];
#pragma unroll
      for (int i = 0; i < 4; ++i) {
        int row = wm * 64 + i * 16 + fr;
        af[i] = *(const bf16x8*)(As + row * 128 + ((ks * 64 + fg * 16) ^ ((row & 7) << 4)));
      }
#pragma unroll
      for (int j = 0; j < 4; ++j) {
        int row = wn * 64 + j * 16 + fr;
        bfr[j] = *(const bf16x8*)(Bs + row * 128 + ((ks * 64 + fg * 16) ^ ((row & 7) << 4)));
      }
#pragma unroll
      for (int i = 0; i < 4; ++i)
#pragma unroll
        for (int j = 0; j < 4; ++j) acc[i][j] = mfma16(af[i], bfr[j], acc[i][j]);
    }
    __syncthreads();
  }
#pragma unroll
  for (int i = 0; i < 4; ++i)
#pragma unroll
    for (int j = 0; j < 4; ++j) {
      int n = n0 + wn * 64 + j * 16 + fr;
      float bias = bo[n];
#pragma unroll
      for (int r = 0; r < 4; ++r) {
        int m = m0 + wm * 64 + i * 16 + fg * 4 + r;
        outp[(size_t)m * nD + n] = acc[i][j][r] + bias + x[(size_t)m * nD + n];
      }
    }
}

// ---------------- LayerNorm (in-place on d_out), one wave per row ----------------
__global__ __launch_bounds__(256) void k_ln(const float* outp,
                                            const float* __restrict__ gamma,
                                            const float* __restrict__ beta,
                                            float* y) {
  int t = threadIdx.x, lane = t & 63, w = t >> 6;
  int row = blockIdx.x * 4 + w;
  const float* rp = outp + (size_t)row * nD;
  float v[12], s1 = 0.f, s2 = 0.f;
#pragma unroll
  for (int i = 0; i < 12; ++i) {
    v[i] = rp[lane + i * 64];
    s1 += v[i];
    s2 += v[i] * v[i];
  }
#pragma unroll
  for (int d = 1; d < 64; d <<= 1) {
    s1 += __shfl_xor(s1, d);
    s2 += __shfl_xor(s2, d);
  }
  float mu = s1 * (1.f / 768.f);
  float var = s2 * (1.f / 768.f) - mu * mu;
  float rstd = rsqrtf(var + LN_EPS);
  float* yp = y + (size_t)row * nD;
#pragma unroll
  for (int i = 0; i < 12; ++i) {
    int n = lane + i * 64;
    yp[n] = (v[i] - mu) * rstd * gamma[n] + beta[n];
  }
}

extern "C" void kernel_launch(void* const* d_in, const int* in_sizes, int n_in,
                              void* d_out, int out_size, void* d_ws, size_t ws_size,
                              hipStream_t stream) {
  const float* x = (const float*)d_in[0];
  const float* Wq = (const float*)d_in[1];
  const float* Wp = (const float*)d_in[2];
  const float* Wk = (const float*)d_in[3];
  const float* Wv = (const float*)d_in[4];
  const float* Wo = (const float*)d_in[5];
  const float* bo = (const float*)d_in[6];
  const float* gamma = (const float*)d_in[7];
  const float* beta = (const float*)d_in[8];
  const float* dt = (const float*)d_in[9];
  const float* gate = (const float*)d_in[10];

  char* ws = (char*)d_ws;
  const size_t szb = (size_t)nM * nD * 2;  // 6,291,456 bytes per bf16 [4096][768]
  bf16* xb = (bf16*)(ws + 0 * szb);        // reused as qn after QPKV GEMM
  bf16* qf = (bf16*)(ws + 1 * szb);
  bf16* pf = (bf16*)(ws + 2 * szb);
  bf16* kf_ = (bf16*)(ws + 3 * szb);
  bf16* vt = (bf16*)(ws + 4 * szb);
  bf16* wt = (bf16*)(ws + 5 * szb);  // 5 * 768*768 bf16 = 5,898,240 bytes
  bf16* qn = xb;
  float* outp = (float*)d_out;  // out-GEMM result, LN runs in place

  k_prep_x<<<dim3(nM * nD / 1024), dim3(256), 0, stream>>>(x, xb);
  k_prep_w<<<dim3(12, 12, 5), dim3(256), 0, stream>>>(Wq, Wp, Wk, Wv, Wo, wt);
  k_gemm_qpkv<<<dim3(6, 32, 4), dim3(256), 0, stream>>>(xb, wt, qf, pf, kf_, vt);
  k_attn<<<dim3(768), dim3(256), 0, stream>>>(qf, pf, kf_, vt, dt, gate, qn);
  k_gemm_out<<<dim3(6, 32), dim3(256), 0, stream>>>(qn, wt + 4 * (size_t)nD * nD, bo, x, outp);
  k_ln<<<dim3(nM / 4), dim3(256), 0, stream>>>(outp, gamma, beta, (float*)d_out);
}